// Round 1
// 5788.827 us; speedup vs baseline: 2.6702x; 2.6702x over previous
//
#include <hip/hip_runtime.h>
#include <stddef.h>

// LSTM encoder: B=64, T=512, H=512, L=4.
// R6: latency-restructured fused loop.
//  - Split flags: flg_h certifies {h-ring[t], x-reads of step t done};
//    flg_x certifies {INP[t-1] published}. Publish RMW leaves the
//    recurrence-certification path; residual loads issued at iteration top
//    (certified by PREVIOUS step's poll A).
//  - Load/latency overlap: x half-A loads issued before poll B (flag spin
//    overlaps fabric latency), h-ring loads issued right after poll B,
//    x half-B loads issued under half-A MFMAs.
//  - One-shot h staging (no halves), 64KB dynamic-LDS stage buffer
//    (x halves at 0/32K, h overlaid after x MFMAs), total 89KB dyn LDS.
//  - XOR swizzle ((row&7)<<4) on stage buffer, stride-17 z tile: kills
//    the 1.54e8 LDS bank-conflict cycles of R5.
// Structure otherwise as R5: 128 WGs = 4 layer-groups x 32; wave = gate;
// U/W as MFMA B-frags in VGPRs; agent-scope relaxed atomics + vmcnt(0)
// before flags; one-vmem ballot polls.
// Workspace (~209.0 MB):
//   XW    fp16 [T][32][4][64][16]  128 MB
//   INP   fp32 [T,B,H]              64 MB
//   WBF   bf16 [L][4H][H] (B^T)      8 MB
//   UBF   bf16 [L][4H][H] (B^T)      8 MB
//   FLGH  int  [L][513][32]        257 KB
//   FLGX  int  [L][513][32]        257 KB
//   HRING bf16 [2][L][64][512]     512 KB

typedef float          f32x4 __attribute__((ext_vector_type(4)));
typedef short          s16x8 __attribute__((ext_vector_type(8)));
typedef unsigned short u16;
typedef u16            u16x4 __attribute__((ext_vector_type(4)));
typedef unsigned long long u64;

__device__ __forceinline__ u16 f2bf(float f) {
    unsigned int u = __builtin_bit_cast(unsigned int, f);
    u += 0x7FFFu + ((u >> 16) & 1u);   // round-to-nearest-even
    return (u16)(u >> 16);
}
__device__ __forceinline__ float sig(float x) { return 1.f / (1.f + __expf(-x)); }
__device__ __forceinline__ float th(float x)  { return 2.f / (1.f + __expf(-2.f * x)) - 1.f; }
__device__ __forceinline__ u64 pk2(float a, float b) {
    return (u64)__builtin_bit_cast(unsigned, a) | ((u64)__builtin_bit_cast(unsigned, b) << 32);
}
__device__ __forceinline__ float lo32(u64 v) { return __builtin_bit_cast(float, (unsigned)v); }
__device__ __forceinline__ float hi32(u64 v) { return __builtin_bit_cast(float, (unsigned)(v >> 32)); }
__device__ __forceinline__ u64 ald(const u64* p) {
    return __hip_atomic_load(p, __ATOMIC_RELAXED, __HIP_MEMORY_SCOPE_AGENT);
}
__device__ __forceinline__ void ast(u64* p, u64 v) {
    __hip_atomic_store(p, v, __ATOMIC_RELAXED, __HIP_MEMORY_SCOPE_AGENT);
}

// all-lane flag poll: lanes with active==false auto-pass
__device__ __forceinline__ void pollflags(const int* p, bool active) {
    while (1) {
        int v = 1;
        if (active) v = __hip_atomic_load(p, __ATOMIC_RELAXED, __HIP_MEMORY_SCOPE_AGENT);
        if (__ballot(v != 0) == ~0ull) break;
    }
}

__global__ void init_flags(int* __restrict__ flg) {
    int i = blockIdx.x * 256 + threadIdx.x;
    if (i < 2 * 4 * 513 * 32) flg[i] = 0;
}

// x[B,T,H] fp32 -> INP[T,B,H] fp32
__global__ void convert_x(const float* __restrict__ x, float* __restrict__ inp) {
#pragma unroll
    for (int i = 0; i < 8; ++i) {
        int f = blockIdx.x * 2048 + i * 256 + threadIdx.x;
        int h4 = f & 127, b = (f >> 7) & 63, t = f >> 13;
        f32x4 v = *(const f32x4*)(x + ((size_t)b * 512 + t) * 512 + h4 * 4);
        *(f32x4*)(inp + ((size_t)t * 64 + b) * 512 + h4 * 4) = v;
    }
}

// W/U [l][k][n] fp32 -> [l][n][k] bf16 (transposed via LDS tile)
__global__ void convert_wu(const float* __restrict__ W, const float* __restrict__ U,
                           u16* __restrict__ WBF, u16* __restrict__ UBF) {
    __shared__ float tl[32][33];
    const int l = blockIdx.z & 3, which = blockIdx.z >> 2;
    const float* src = (which ? U : W) + (size_t)l * 512 * 2048;
    u16* dst = (which ? UBF : WBF) + (size_t)l * 2048 * 512;
    const int n0 = blockIdx.x * 32, k0 = blockIdx.y * 32;
    const int tid = threadIdx.x;
    const int r = tid >> 3, c4 = (tid & 7) * 4;
    f32x4 v = *(const f32x4*)(src + (size_t)(k0 + r) * 2048 + n0 + c4);
    tl[r][c4 + 0] = v[0]; tl[r][c4 + 1] = v[1]; tl[r][c4 + 2] = v[2]; tl[r][c4 + 3] = v[3];
    __syncthreads();
    u16x4 o = { f2bf(tl[c4 + 0][r]), f2bf(tl[c4 + 1][r]), f2bf(tl[c4 + 2][r]), f2bf(tl[c4 + 3][r]) };
    *(u16x4*)(dst + (size_t)(n0 + r) * 512 + k0 + c4) = o;
}

// layer-0 xW: C fp16 = A[32768,512] fp32 @ Bt^T + bias, output in
// [t][wg][gate][b][ul] layout (per-(t,wg) contiguous 8KB slices)
__global__ __launch_bounds__(256) void gemm_xw(const float* __restrict__ A,
                                               const u16* __restrict__ Bt,
                                               const float* __restrict__ bias,
                                               _Float16* __restrict__ C) {
    __shared__ u16 Alds[128][72];
    __shared__ u16 Blds[128][72];
    const int tid = threadIdx.x, lane = tid & 63, wave = tid >> 6;
    const int m0 = blockIdx.y * 128, n0 = blockIdx.x * 128;
    const int wm = (wave & 1) * 64, wn = (wave >> 1) * 64;
    const int m_l = lane & 15, k_l = (lane >> 4) * 8, r0 = (lane >> 4) * 4;
    f32x4 acc[4][4] = {};
    for (int k0 = 0; k0 < 512; k0 += 64) {
        __syncthreads();
#pragma unroll
        for (int i = 0; i < 8; ++i) {
            int f = tid + i * 256;
            int row = f >> 4, c4 = (f & 15) * 4;
            f32x4 v = *(const f32x4*)(A + (size_t)(m0 + row) * 512 + k0 + c4);
            u16x4 bv = { f2bf(v[0]), f2bf(v[1]), f2bf(v[2]), f2bf(v[3]) };
            *(u16x4*)&Alds[row][c4] = bv;
        }
#pragma unroll
        for (int i = 0; i < 4; ++i) {
            int f = tid + i * 256;
            int row = f >> 3, c8 = (f & 7) * 8;
            *(s16x8*)&Blds[row][c8] = *(const s16x8*)(Bt + (size_t)(n0 + row) * 512 + k0 + c8);
        }
        __syncthreads();
#pragma unroll
        for (int kk = 0; kk < 2; ++kk) {
            s16x8 af[4], bfr[4];
            const int kb = kk * 32 + k_l;
#pragma unroll
            for (int mi = 0; mi < 4; ++mi) af[mi]  = *(const s16x8*)&Alds[wm + mi * 16 + m_l][kb];
#pragma unroll
            for (int ni = 0; ni < 4; ++ni) bfr[ni] = *(const s16x8*)&Blds[wn + ni * 16 + m_l][kb];
#pragma unroll
            for (int mi = 0; mi < 4; ++mi)
#pragma unroll
                for (int ni = 0; ni < 4; ++ni)
                    acc[mi][ni] = __builtin_amdgcn_mfma_f32_16x16x32_bf16(af[mi], bfr[ni], acc[mi][ni], 0, 0, 0);
        }
    }
#pragma unroll
    for (int ni = 0; ni < 4; ++ni) {
        const int col = n0 + wn + ni * 16 + m_l;
        const float bb = bias[col];
        const int gate = col >> 9, uu = col & 511, wgi = uu >> 4, ul = uu & 15;
#pragma unroll
        for (int mi = 0; mi < 4; ++mi)
#pragma unroll
            for (int r = 0; r < 4; ++r) {
                const int m = m0 + wm + mi * 16 + r0 + r;
                const int t = m >> 6, brow = m & 63;
                C[(((size_t)t * 32 + wgi) * 4 + gate) * 1024 + brow * 16 + ul] =
                    (_Float16)(acc[mi][ni][r] + bb);
            }
    }
}

// Fused persistent kernel: 128 WGs = 4 layer-groups x 32.
__global__ __launch_bounds__(256, 1) void fused(const _Float16* __restrict__ XW,
                                                const u16* __restrict__ WBF,
                                                const u16* __restrict__ UBF,
                                                const float* __restrict__ bias,
                                                float* __restrict__ INP,
                                                int* __restrict__ flgh,
                                                int* __restrict__ flgx,
                                                u64* __restrict__ hring,   // [2][4][64][128] u64
                                                float* __restrict__ states) {
    extern __shared__ char lds[];
    u16*   stage  = (u16*)lds;                 // 64KB: x halves @0/@32768 (rows [64][256] bf16,
                                               //       stride 512B); h [64][512] overlaid, stride 1024B
    u16*   xw_lds = (u16*)(lds + 65536);       // 8KB: layer-0 xW slice [gate][b][ul] fp16
    float* z_lds  = (float*)(lds + 73728);     // 17408B: [4][64][17] f32 (stride-17 = conflict-free)

    const int tid = threadIdx.x, lane = tid & 63, wave = tid >> 6;
    const int l = blockIdx.x & 3, wg = blockIdx.x >> 2;
    const int m_l = lane & 15, q16 = lane >> 4;
    const int k_l = q16 * 8, r0 = q16 * 4;
    const int gb = tid >> 2, ug = (tid & 3) * 4, u = wg * 16 + ug;

    // weight fragments in VGPRs (MFMA B-frag layout)
    s16x8 ufrag[16], wfrag[16];
    {
        const u16* ub = UBF + (size_t)l * 1048576 + ((size_t)(wave * 512 + wg * 16 + m_l)) * 512 + k_l;
#pragma unroll
        for (int kf = 0; kf < 16; ++kf) ufrag[kf] = *(const s16x8*)(ub + kf * 32);
    }
    if (l > 0) {
        const u16* wb = WBF + (size_t)l * 1048576 + ((size_t)(wave * 512 + wg * 16 + m_l)) * 512 + k_l;
#pragma unroll
        for (int kf = 0; kf < 16; ++kf) wfrag[kf] = *(const s16x8*)(wb + kf * 32);
    }
    float bj[4][4];
#pragma unroll
    for (int g = 0; g < 4; ++g)
#pragma unroll
        for (int j = 0; j < 4; ++j)
            bj[g][j] = (l > 0) ? bias[(size_t)l * 2048 + g * 512 + u + j] : 0.f;

    s16x8 xr0 = {}, xr1 = {};              // one-step-ahead XW stage regs (l==0)
    if (l == 0) {
        const s16x8* p = (const s16x8*)(XW + (size_t)wg * 4096 + tid * 16);
        xr0 = p[0]; xr1 = p[1];
    }

    float cr[4]    = {0.f, 0.f, 0.f, 0.f};
    float hprev[4] = {0.f, 0.f, 0.f, 0.f};

    for (int t = 0; t <= 512; ++t) {
        const bool do_x = (l > 0) && (t < 512);
        const bool do_h = (t > 0) && (t < 512);
        const bool last = (t == 512);

        // stage this step's XW into LDS; issue next step's loads (l==0)
        if (l == 0 && !last) {
            *(s16x8*)&xw_lds[tid * 16]     = xr0;
            *(s16x8*)&xw_lds[tid * 16 + 8] = xr1;
            if (t < 511) {
                const s16x8* p = (const s16x8*)(XW + ((size_t)(t + 1) * 32 + wg) * 4096 + tid * 16);
                xr0 = p[0]; xr1 = p[1];
            }
        }
        // residual prefetch: INP[t-1] was certified by PREVIOUS step's poll A
        u64 rr0 = 0, rr1 = 0;
        u64* op = (u64*)(INP + (size_t)(t > 0 ? t - 1 : 0) * 32768 + gb * 512 + u);
        if (t > 0 && l > 0) { rr0 = ald(op); rr1 = ald(op + 1); }

        // poll A: x availability (producer's flg_x[t+1] certifies out_{l-1}[t])
        if (do_x) pollflags(flgx + ((size_t)(l - 1) * 513 + t + 1) * 32 + (lane & 31), lane < 32);

        u64 xa[32], xb[32], hv[32];
        const u64* xs = (const u64*)(INP + (size_t)t * 32768);
        if (do_x) {
            // issue x half-A loads BEFORE poll B: latency overlaps the flag spin
#pragma unroll
            for (int i = 0; i < 32; ++i) {
                int j = tid + i * 256;
                xa[i] = ald(xs + (j >> 7) * 256 + (j & 127));
            }
        }
        // poll B: own recurrence (all 32 WGs of this group finished step t-1)
        if (t > 0) pollflags(flgh + ((size_t)l * 513 + t - 1) * 32 + (lane & 31), lane < 32);
        if (do_h) {
            // issue h loads immediately; they land under the x MFMAs
            const u64* hs = hring + (((size_t)((t - 1) & 1) * 4 + l) << 13);
#pragma unroll
            for (int i = 0; i < 32; ++i) hv[i] = ald(hs + tid + i * 256);
        }

        f32x4 acc[4] = {};
        if (do_x) {                        // x phases: z += x@W
#pragma unroll
            for (int i = 0; i < 32; ++i) {
                int j = tid + i * 256;
                int row = j >> 7, kp = j & 127;
                unsigned pkv = (unsigned)f2bf(lo32(xa[i])) | ((unsigned)f2bf(hi32(xa[i])) << 16);
                *(unsigned*)((char*)stage + row * 512 + ((kp * 4) ^ ((row & 7) << 4))) = pkv;
            }
            __syncthreads();
            // issue half-B loads under half-A MFMAs
#pragma unroll
            for (int i = 0; i < 32; ++i) {
                int j = tid + i * 256;
                xb[i] = ald(xs + (j >> 7) * 256 + (j & 127) + 128);
            }
#pragma unroll
            for (int kf = 0; kf < 8; ++kf)
#pragma unroll
                for (int mt = 0; mt < 4; ++mt) {
                    int row = mt * 16 + m_l;
                    s16x8 af = *(const s16x8*)((char*)stage + row * 512 +
                                               ((kf * 64 + q16 * 16) ^ ((row & 7) << 4)));
                    acc[mt] = __builtin_amdgcn_mfma_f32_16x16x32_bf16(af, wfrag[kf], acc[mt], 0, 0, 0);
                }
#pragma unroll
            for (int i = 0; i < 32; ++i) {
                int j = tid + i * 256;
                int row = j >> 7, kp = j & 127;
                unsigned pkv = (unsigned)f2bf(lo32(xb[i])) | ((unsigned)f2bf(hi32(xb[i])) << 16);
                *(unsigned*)((char*)stage + 32768 + row * 512 + ((kp * 4) ^ ((row & 7) << 4))) = pkv;
            }
            __syncthreads();
#pragma unroll
            for (int kf = 0; kf < 8; ++kf)
#pragma unroll
                for (int mt = 0; mt < 4; ++mt) {
                    int row = mt * 16 + m_l;
                    s16x8 af = *(const s16x8*)((char*)stage + 32768 + row * 512 +
                                               ((kf * 64 + q16 * 16) ^ ((row & 7) << 4)));
                    acc[mt] = __builtin_amdgcn_mfma_f32_16x16x32_bf16(af, wfrag[8 + kf], acc[mt], 0, 0, 0);
                }
            __syncthreads();               // x region free -> h overlays it
        }
        if (do_h) {                        // h phase: z += h_{t-1}@U, one-shot
#pragma unroll
            for (int i = 0; i < 32; ++i) {
                int j = tid + i * 256;
                int row = j >> 7, kq = j & 127;
                *(u64*)((char*)stage + row * 1024 + ((kq * 8) ^ ((row & 7) << 4))) = hv[i];
            }
            __syncthreads();
#pragma unroll
            for (int kf = 0; kf < 16; ++kf)
#pragma unroll
                for (int mt = 0; mt < 4; ++mt) {
                    int row = mt * 16 + m_l;
                    s16x8 af = *(const s16x8*)((char*)stage + row * 1024 +
                                               ((kf * 64 + q16 * 16) ^ ((row & 7) << 4)));
                    acc[mt] = __builtin_amdgcn_mfma_f32_16x16x32_bf16(af, ufrag[kf], acc[mt], 0, 0, 0);
                }
        }

        float hn[4] = {0.f, 0.f, 0.f, 0.f};
        if (!last) {
            // z exchange (stride-17: conflict-free both directions)
#pragma unroll
            for (int mt = 0; mt < 4; ++mt)
#pragma unroll
                for (int r = 0; r < 4; ++r)
                    z_lds[wave * 1088 + (mt * 16 + r0 + r) * 17 + m_l] = acc[mt][r];
            __syncthreads();

            // gate phase: thread handles 4 units of batch row gb
#pragma unroll
            for (int j = 0; j < 4; ++j) {
                float zi = z_lds[0 * 1088 + gb * 17 + ug + j];
                float zf = z_lds[1 * 1088 + gb * 17 + ug + j];
                float zg = z_lds[2 * 1088 + gb * 17 + ug + j];
                float zo = z_lds[3 * 1088 + gb * 17 + ug + j];
                if (l == 0) {
                    zi += (float)*(const _Float16*)&xw_lds[0 * 1024 + gb * 16 + ug + j];
                    zf += (float)*(const _Float16*)&xw_lds[1 * 1024 + gb * 16 + ug + j];
                    zg += (float)*(const _Float16*)&xw_lds[2 * 1024 + gb * 16 + ug + j];
                    zo += (float)*(const _Float16*)&xw_lds[3 * 1024 + gb * 16 + ug + j];
                } else {
                    zi += bj[0][j]; zf += bj[1][j]; zg += bj[2][j]; zo += bj[3][j];
                }
                float cc = sig(zf) * cr[j] + sig(zi) * th(zg);
                cr[j] = cc;
                hn[j] = sig(zo) * th(cc);
            }
            // publish h -> ring slot (t&1, l), then raise recurrence flag
            u16x4 hb = { f2bf(hn[0]), f2bf(hn[1]), f2bf(hn[2]), f2bf(hn[3]) };
            ast(hring + (((size_t)(t & 1) * 4 + l) << 13) + gb * 128 + (u >> 2),
                __builtin_bit_cast(u64, hb));
            asm volatile("s_waitcnt vmcnt(0)" ::: "memory");
            __syncthreads();
            if (tid == 0)
                __hip_atomic_store(flgh + ((size_t)l * 513 + t) * 32 + wg, 1,
                                   __ATOMIC_RELAXED, __HIP_MEMORY_SCOPE_AGENT);
        }

        // publish out_l[t-1] = hprev (+ residual) into INP — OFF the recurrence
        // certification path (residual values prefetched at iteration top)
        if (t > 0) {
            float o0 = hprev[0], o1 = hprev[1], o2 = hprev[2], o3 = hprev[3];
            if (l > 0) { o0 += lo32(rr0); o1 += hi32(rr0); o2 += lo32(rr1); o3 += hi32(rr1); }
            ast(op,     pk2(o0, o1));
            ast(op + 1, pk2(o2, o3));
            if (l == 0 && last) {
                f32x4 sv = { o0, o1, o2, o3 };
#pragma unroll
                for (int rep = 0; rep < 4; ++rep)
                    *(f32x4*)&states[(size_t)rep * 32768 + gb * 512 + u] = sv;
            }
        }
#pragma unroll
        for (int j = 0; j < 4; ++j) hprev[j] = hn[j];

        asm volatile("s_waitcnt vmcnt(0)" ::: "memory");
        __syncthreads();
        if (tid == 0 && l < 3 && t > 0)
            __hip_atomic_store(flgx + ((size_t)l * 513 + t) * 32 + wg, 1,
                               __ATOMIC_RELAXED, __HIP_MEMORY_SCOPE_AGENT);
    }
}

// INP[T,B,H] -> out[B,T,H]
__global__ void transpose_out(const float* __restrict__ inp, float* __restrict__ out) {
#pragma unroll
    for (int i = 0; i < 8; ++i) {
        int f = blockIdx.x * 2048 + i * 256 + threadIdx.x;
        int h4 = f & 127, t = (f >> 7) & 511, b = f >> 16;
        f32x4 v = *(const f32x4*)(inp + ((size_t)t * 64 + b) * 512 + h4 * 4);
        *(f32x4*)(out + ((size_t)b * 512 + t) * 512 + h4 * 4) = v;
    }
}

extern "C" void kernel_launch(void* const* d_in, const int* in_sizes, int n_in,
                              void* d_out, int out_size, void* d_ws, size_t ws_size,
                              hipStream_t stream) {
    const float* x = (const float*)d_in[0];
    const float* W = (const float*)d_in[1];
    const float* U = (const float*)d_in[2];
    const float* b = (const float*)d_in[3];
    float* out = (float*)d_out;
    char* ws = (char*)d_ws;

    constexpr size_t XW_OFF   = 0;                         // 134,217,728
    constexpr size_t INP_OFF  = 134217728;                 //  67,108,864
    constexpr size_t WBF_OFF  = INP_OFF + 67108864;        //   8,388,608
    constexpr size_t UBF_OFF  = WBF_OFF + 8388608;         //   8,388,608
    constexpr size_t FLGH_OFF = UBF_OFF + 8388608;         //     262,656
    constexpr size_t FLGX_OFF = FLGH_OFF + 262656;         //     262,656
    constexpr size_t HR_OFF   = FLGX_OFF + 262656;         //     524,288

    _Float16* XW  = (_Float16*)(ws + XW_OFF);
    float*    INP = (float*)(ws + INP_OFF);
    u16*      WBF = (u16*)(ws + WBF_OFF);
    u16*      UBF = (u16*)(ws + UBF_OFF);
    int*      flgh = (int*)(ws + FLGH_OFF);
    int*      flgx = (int*)(ws + FLGX_OFF);
    u64*      hring = (u64*)(ws + HR_OFF);

    constexpr int FUSED_LDS = 91136;       // 64K stage + 8K xw + 17408 z
    static int attr_done = 0;
    if (!attr_done) {
        (void)hipFuncSetAttribute((const void*)fused,
                                  hipFuncAttributeMaxDynamicSharedMemorySize, FUSED_LDS);
        attr_done = 1;
    }

    init_flags<<<(2 * 4 * 513 * 32 + 255) / 256, 256, 0, stream>>>(flgh);
    convert_x<<<2048, 256, 0, stream>>>(x, INP);
    convert_wu<<<dim3(64, 16, 8), 256, 0, stream>>>(W, U, WBF, UBF);
    gemm_xw<<<dim3(16, 256), 256, 0, stream>>>(INP, WBF, b, XW);
    fused<<<128, 256, FUSED_LDS, stream>>>(XW, WBF, UBF, b, INP, flgh, flgx, hring, out + 16777216);
    transpose_out<<<2048, 256, 0, stream>>>(INP, out);
}

// Round 3
// 3866.791 us; speedup vs baseline: 3.9974x; 1.4971x over previous
//
#include <hip/hip_runtime.h>
#include <stddef.h>

// LSTM encoder: B=64, T=512, H=512, L=4.
// R8 = R7 (decoupled projection) with layer 0 unified into the projection
// scheme and the 128MB XW0 buffer + gemm_xw kernel removed (workspace now
// ~124MB, well under the proven ~219MB envelope — R7's container failure is
// suspected ws overflow). 256 persistent WGs:
//   - 128 recurrence WGs (4 layers x 32 unit-slices): per step only
//     {poll flgh -> h ring load -> LDS stage -> 64 MFMA (h@U) -> gates ->
//      publish}. XW slice (x@W+b, fp16 [gate][unit][batch]) prefetched into
//     regs one step ahead from the 8-deep XWR ring (flag flgp).
//   - 128 projection WGs (4 layers x 32): layer 0 reads XB (bf16 copy of x,
//     ready at launch, no poll); layers 1..3 read the 16-deep INPB ring
//     (bf16 out_{l-1} published by recurrence, certified by flgx).
//     Compute x@W+bias, write XWR slot t&7, raise flgp.
// Flag-dependency graph is a DAG (every cycle candidate nets <= -8 in t):
//   flgh[l][t] -> {flgh[l][t-1], flgp[l][t], flgp[l+1][t-18]}
//   flgp[l][t] -> {flgp[l][t-1], flgx[l-1][t+1], flgh[l][t-8]}
//   flgx[l][t] -> {flgh[l][t], flgp[l][t+1], flgp[l+1][t-17]}
// All cross-WG data uses agent-scope relaxed atomics; flag raises follow
// s_waitcnt vmcnt(0); polls are issued "clean".
// Workspace (~124.3 MB):
//   XB    bf16 [T][64][512]          32 MB   x in [t][batch][h] slices
//   INP   fp32 [T,B,H]               64 MB   out_0 -> ... -> out_3 in place
//   WBF   bf16 [L][4H][H] (B^T)       8 MB
//   UBF   bf16 [L][4H][H] (B^T)       8 MB
//   FLGH  int  [L][513][32]         257 KB   recurrence step done
//   FLGX  int  [L][513][32]         257 KB   out_l[t-1] published
//   FLGP  int  [L][512][32]         256 KB   XW slice ready
//   HRING bf16 [2][L][64][512]      512 KB   h double-ring
//   XWR   fp16 [L][8][32][4][16][64]  8 MB   XW ring
//   INPB  bf16 [3][16][64][512]       3 MB   out_l ring (layers 0..2)

typedef float          f32x4 __attribute__((ext_vector_type(4)));
typedef short          s16x8 __attribute__((ext_vector_type(8)));
typedef unsigned short u16;
typedef u16            u16x4 __attribute__((ext_vector_type(4)));
typedef _Float16       f16x4 __attribute__((ext_vector_type(4)));
typedef unsigned long long u64;

__device__ __forceinline__ u16 f2bf(float f) {
    unsigned int u = __builtin_bit_cast(unsigned int, f);
    u += 0x7FFFu + ((u >> 16) & 1u);   // round-to-nearest-even
    return (u16)(u >> 16);
}
__device__ __forceinline__ float sig(float x) { return 1.f / (1.f + __expf(-x)); }
__device__ __forceinline__ float th(float x)  { return 2.f / (1.f + __expf(-2.f * x)) - 1.f; }
__device__ __forceinline__ u64 pk2(float a, float b) {
    return (u64)__builtin_bit_cast(unsigned, a) | ((u64)__builtin_bit_cast(unsigned, b) << 32);
}
__device__ __forceinline__ float lo32(u64 v) { return __builtin_bit_cast(float, (unsigned)v); }
__device__ __forceinline__ float hi32(u64 v) { return __builtin_bit_cast(float, (unsigned)(v >> 32)); }
__device__ __forceinline__ u64 ald(const u64* p) {
    return __hip_atomic_load(p, __ATOMIC_RELAXED, __HIP_MEMORY_SCOPE_AGENT);
}
__device__ __forceinline__ void ast(u64* p, u64 v) {
    __hip_atomic_store(p, v, __ATOMIC_RELAXED, __HIP_MEMORY_SCOPE_AGENT);
}

// all-lane flag poll: lanes with active==false auto-pass
__device__ __forceinline__ void pollflags(const int* p, bool active) {
    while (1) {
        int v = 1;
        if (active) v = __hip_atomic_load(p, __ATOMIC_RELAXED, __HIP_MEMORY_SCOPE_AGENT);
        if (__ballot(v != 0) == ~0ull) break;
    }
}

__global__ void init_flags(int* __restrict__ flg) {
    int i = blockIdx.x * 256 + threadIdx.x;
    if (i < 196864) flg[i] = 0;   // flgh + flgx + flgp contiguous
}

// x[B,T,H] fp32 -> XB[T][64][512] bf16 (u64 = 4 packed bf16)
__global__ void convert_x(const float* __restrict__ x, u64* __restrict__ XB) {
#pragma unroll
    for (int i = 0; i < 8; ++i) {
        int f = blockIdx.x * 2048 + i * 256 + threadIdx.x;
        int h4 = f & 127, b = (f >> 7) & 63, t = f >> 13;
        f32x4 v = *(const f32x4*)(x + ((size_t)b * 512 + t) * 512 + h4 * 4);
        u16x4 o = { f2bf(v[0]), f2bf(v[1]), f2bf(v[2]), f2bf(v[3]) };
        XB[((size_t)t * 64 + b) * 128 + h4] = __builtin_bit_cast(u64, o);
    }
}

// W/U [l][k][n] fp32 -> [l][n][k] bf16 (transposed via LDS tile)
__global__ void convert_wu(const float* __restrict__ W, const float* __restrict__ U,
                           u16* __restrict__ WBF, u16* __restrict__ UBF) {
    __shared__ float tl[32][33];
    const int l = blockIdx.z & 3, which = blockIdx.z >> 2;
    const float* src = (which ? U : W) + (size_t)l * 512 * 2048;
    u16* dst = (which ? UBF : WBF) + (size_t)l * 2048 * 512;
    const int n0 = blockIdx.x * 32, k0 = blockIdx.y * 32;
    const int tid = threadIdx.x;
    const int r = tid >> 3, c4 = (tid & 7) * 4;
    f32x4 v = *(const f32x4*)(src + (size_t)(k0 + r) * 2048 + n0 + c4);
    tl[r][c4 + 0] = v[0]; tl[r][c4 + 1] = v[1]; tl[r][c4 + 2] = v[2]; tl[r][c4 + 3] = v[3];
    __syncthreads();
    u16x4 o = { f2bf(tl[c4 + 0][r]), f2bf(tl[c4 + 1][r]), f2bf(tl[c4 + 2][r]), f2bf(tl[c4 + 3][r]) };
    *(u16x4*)(dst + (size_t)(n0 + r) * 512 + k0 + c4) = o;
}

// Fused persistent kernel: 128 recurrence WGs + 128 projection WGs.
__global__ __launch_bounds__(256, 1) void fused(const u64* __restrict__ XB,
                                                const u16* __restrict__ WBF,
                                                const u16* __restrict__ UBF,
                                                const float* __restrict__ bias,
                                                float* __restrict__ INP,
                                                int* __restrict__ flgh,
                                                int* __restrict__ flgx,
                                                int* __restrict__ flgp,
                                                u64* __restrict__ hring,   // [2][4][64][128] u64
                                                u64* __restrict__ XWR,     // [4][8][32][1024] u64 (fp16)
                                                u64* __restrict__ INPB,    // [3][16][8192] u64 (bf16)
                                                float* __restrict__ states) {
    extern __shared__ char lds[];
    char*  stage = lds;                    // 64KB: [64 rows][1024B] bf16, XOR-swizzled
    u16*   xw16  = (u16*)(lds + 65536);    // 8KB fp16 slice, layout [gate][unit][batch]
    float* z_lds = (float*)lds;            // overlay [4][64][20] f32 (after MFMA reads)

    const int tid = threadIdx.x, lane = tid & 63, wave = tid >> 6;
    const int m_l = lane & 15, q16 = lane >> 4;
    const int k_l = q16 * 8, r0 = q16 * 4;
    const int gb = tid >> 2, ug = (tid & 3) * 4;

    if (blockIdx.x < 128) {
        // ===================== recurrence role =====================
        const int l = blockIdx.x & 3, wg = blockIdx.x >> 2;
        const int u = wg * 16 + ug;

        s16x8 ufrag[16];
        {
            const u16* ub = UBF + (size_t)l * 1048576 + ((size_t)(wave * 512 + wg * 16 + m_l)) * 512 + k_l;
#pragma unroll
            for (int kf = 0; kf < 16; ++kf) ufrag[kf] = *(const s16x8*)(ub + kf * 32);
        }

        u64 xr[4];
        // prologue: XW[0]
        pollflags(flgp + ((size_t)l * 512 + 0) * 32 + wg, true);
        {
            const u64* p = XWR + ((size_t)(l * 8 + 0) * 32 + wg) * 1024;
#pragma unroll
            for (int k = 0; k < 4; ++k) xr[k] = ald(p + k * 256 + tid);
        }

        float cr[4] = {0.f, 0.f, 0.f, 0.f};
        float hprev[4] = {0.f, 0.f, 0.f, 0.f};

        for (int t = 0; t <= 512; ++t) {
            // ---- critical section: recurrence ----
            if (t > 0) pollflags(flgh + ((size_t)l * 513 + t - 1) * 32 + (lane & 31), lane < 32);

            u64 rr0 = 0, rr1 = 0;
            u64* op = (u64*)(INP + (size_t)(t > 0 ? t - 1 : 0) * 32768 + gb * 512 + u);

            f32x4 acc0[4] = {}, acc1[4] = {};
            if (t > 0 && t < 512) {
                u64 hv[32];
                const u64* hs = hring + (((size_t)((t - 1) & 1) * 4 + l) << 13);
#pragma unroll
                for (int i = 0; i < 32; ++i) hv[i] = ald(hs + tid + i * 256);
                if (l > 0) { rr0 = ald(op); rr1 = ald(op + 1); }   // residual, used late
#pragma unroll
                for (int i = 0; i < 32; ++i) {
                    int j = tid + i * 256, row = j >> 7, kq = j & 127;
                    *(u64*)(stage + row * 1024 + ((kq * 8) ^ ((row & 7) << 4))) = hv[i];
                }
                __syncthreads();
#pragma unroll
                for (int kf = 0; kf < 8; ++kf)
#pragma unroll
                    for (int mt = 0; mt < 4; ++mt) {
                        int row = mt * 16 + m_l;
                        s16x8 af = *(const s16x8*)(stage + row * 1024 +
                                                   ((kf * 64 + q16 * 16) ^ ((row & 7) << 4)));
                        acc0[mt] = __builtin_amdgcn_mfma_f32_16x16x32_bf16(af, ufrag[kf], acc0[mt], 0, 0, 0);
                    }
#pragma unroll
                for (int kf = 8; kf < 16; ++kf)
#pragma unroll
                    for (int mt = 0; mt < 4; ++mt) {
                        int row = mt * 16 + m_l;
                        s16x8 af = *(const s16x8*)(stage + row * 1024 +
                                                   ((kf * 64 + q16 * 16) ^ ((row & 7) << 4)));
                        acc1[mt] = __builtin_amdgcn_mfma_f32_16x16x32_bf16(af, ufrag[kf], acc1[mt], 0, 0, 0);
                    }
                __syncthreads();           // MFMA reads done -> z/xw overlay safe
            } else if (t == 512 && l > 0) {
                rr0 = ald(op); rr1 = ald(op + 1);
            }

            float hn[4] = {0.f, 0.f, 0.f, 0.f};
            if (t < 512) {
#pragma unroll
                for (int mt = 0; mt < 4; ++mt)
#pragma unroll
                    for (int r = 0; r < 4; ++r)
                        z_lds[wave * 1280 + (mt * 16 + r0 + r) * 20 + m_l] = acc0[mt][r] + acc1[mt][r];
                {   // xw slice regs -> LDS (quarter-interleaved b64 writes)
                    u64* xp = (u64*)xw16;
#pragma unroll
                    for (int k = 0; k < 4; ++k) xp[k * 256 + tid] = xr[k];
                }
                __syncthreads();
                f32x4 zv[4];
#pragma unroll
                for (int g = 0; g < 4; ++g) zv[g] = *(const f32x4*)&z_lds[g * 1280 + gb * 20 + ug];
                const _Float16* xwf = (const _Float16*)xw16;
#pragma unroll
                for (int jj = 0; jj < 4; ++jj) {
                    float zi = zv[0][jj] + (float)xwf[0 * 1024 + (ug + jj) * 64 + gb];
                    float zf = zv[1][jj] + (float)xwf[1 * 1024 + (ug + jj) * 64 + gb];
                    float zg = zv[2][jj] + (float)xwf[2 * 1024 + (ug + jj) * 64 + gb];
                    float zo = zv[3][jj] + (float)xwf[3 * 1024 + (ug + jj) * 64 + gb];
                    float cc = sig(zf) * cr[jj] + sig(zi) * th(zg);
                    cr[jj] = cc;
                    hn[jj] = sig(zo) * th(cc);
                }
                u16x4 hb = { f2bf(hn[0]), f2bf(hn[1]), f2bf(hn[2]), f2bf(hn[3]) };
                ast(hring + (((size_t)(t & 1) * 4 + l) << 13) + gb * 128 + (u >> 2),
                    __builtin_bit_cast(u64, hb));
                asm volatile("s_waitcnt vmcnt(0)" ::: "memory");
                __syncthreads();
                if (tid == 0)
                    __hip_atomic_store(flgh + ((size_t)l * 513 + t) * 32 + wg, 1,
                                       __ATOMIC_RELAXED, __HIP_MEMORY_SCOPE_AGENT);
            }

            // ---- off-critical: XW prefetch for t+1 ----
            if (t < 511) {
                pollflags(flgp + ((size_t)l * 512 + (t + 1)) * 32 + wg, true);
                const u64* p = XWR + ((size_t)(l * 8 + ((t + 1) & 7)) * 32 + wg) * 1024;
#pragma unroll
                for (int k = 0; k < 4; ++k) xr[k] = ald(p + k * 256 + tid);
            }

            // ---- off-critical: publish out_l[t-1] = hprev (+ residual) ----
            if (t > 0) {
                if (l < 3 && t >= 17)   // INPB ring backpressure (16-deep, cold)
                    pollflags(flgp + ((size_t)(l + 1) * 512 + (t - 17)) * 32 + (lane & 31), lane < 32);
                float o0 = hprev[0], o1 = hprev[1], o2 = hprev[2], o3 = hprev[3];
                if (l > 0) { o0 += lo32(rr0); o1 += hi32(rr0); o2 += lo32(rr1); o3 += hi32(rr1); }
                ast(op,     pk2(o0, o1));
                ast(op + 1, pk2(o2, o3));
                if (l < 3) {
                    u16x4 ob = { f2bf(o0), f2bf(o1), f2bf(o2), f2bf(o3) };
                    ast(INPB + ((size_t)l * 16 + ((t - 1) & 15)) * 8192 + gb * 128 + (u >> 2),
                        __builtin_bit_cast(u64, ob));
                }
                if (l == 0 && t == 512) {
                    f32x4 sv = { o0, o1, o2, o3 };
#pragma unroll
                    for (int rep = 0; rep < 4; ++rep)
                        *(f32x4*)&states[(size_t)rep * 32768 + gb * 512 + u] = sv;
                }
                asm volatile("s_waitcnt vmcnt(0)" ::: "memory");
                __syncthreads();
                if (tid == 0 && l < 3)
                    __hip_atomic_store(flgx + ((size_t)l * 513 + t) * 32 + wg, 1,
                                       __ATOMIC_RELAXED, __HIP_MEMORY_SCOPE_AGENT);
            }
#pragma unroll
            for (int jj = 0; jj < 4; ++jj) if (t < 512) hprev[jj] = hn[jj];
        }
    } else {
        // ===================== projection role =====================
        const int pid = blockIdx.x - 128;
        const int l = pid & 3, wg = pid >> 2;

        s16x8 wfrag[16];
        {
            const u16* wb = WBF + (size_t)l * 1048576 + ((size_t)(wave * 512 + wg * 16 + m_l)) * 512 + k_l;
#pragma unroll
            for (int kf = 0; kf < 16; ++kf) wfrag[kf] = *(const s16x8*)(wb + kf * 32);
        }
        const float bj = bias[(size_t)l * 2048 + wave * 512 + wg * 16 + m_l];

        for (int t = 0; t < 512; ++t) {
            // input availability (layer 0's XB is ready at launch)
            if (l > 0) pollflags(flgx + ((size_t)(l - 1) * 513 + t + 1) * 32 + (lane & 31), lane < 32);
            // XWR ring backpressure (8-deep; rec consumed slot by flgh[l][t-8])
            if (t >= 8) pollflags(flgh + ((size_t)l * 513 + (t - 8)) * 32 + wg, true);

            u64 xa[32];
            if (l == 0) {
                const u64* xs = XB + (size_t)t * 8192;
#pragma unroll
                for (int i = 0; i < 32; ++i) xa[i] = xs[tid + i * 256];
            } else {
                const u64* xs = INPB + ((size_t)(l - 1) * 16 + (t & 15)) * 8192;
#pragma unroll
                for (int i = 0; i < 32; ++i) xa[i] = ald(xs + tid + i * 256);
            }
#pragma unroll
            for (int i = 0; i < 32; ++i) {
                int j = tid + i * 256, row = j >> 7, kq = j & 127;
                *(u64*)(stage + row * 1024 + ((kq * 8) ^ ((row & 7) << 4))) = xa[i];
            }
            __syncthreads();

            f32x4 acc0[4] = {}, acc1[4] = {};
#pragma unroll
            for (int kf = 0; kf < 8; ++kf)
#pragma unroll
                for (int mt = 0; mt < 4; ++mt) {
                    int row = mt * 16 + m_l;
                    s16x8 af = *(const s16x8*)(stage + row * 1024 +
                                               ((kf * 64 + q16 * 16) ^ ((row & 7) << 4)));
                    acc0[mt] = __builtin_amdgcn_mfma_f32_16x16x32_bf16(af, wfrag[kf], acc0[mt], 0, 0, 0);
                }
#pragma unroll
            for (int kf = 8; kf < 16; ++kf)
#pragma unroll
                for (int mt = 0; mt < 4; ++mt) {
                    int row = mt * 16 + m_l;
                    s16x8 af = *(const s16x8*)(stage + row * 1024 +
                                               ((kf * 64 + q16 * 16) ^ ((row & 7) << 4)));
                    acc1[mt] = __builtin_amdgcn_mfma_f32_16x16x32_bf16(af, wfrag[kf], acc1[mt], 0, 0, 0);
                }
            __syncthreads();               // stage reads done before next-iter overwrite

            // epilogue: fp16(acc + bias) -> XWR slot, layout [gate][unit][batch]
            u64* xd = XWR + ((size_t)(l * 8 + (t & 7)) * 32 + wg) * 1024;
#pragma unroll
            for (int mt = 0; mt < 4; ++mt) {
                f16x4 pk = { (_Float16)(acc0[mt][0] + acc1[mt][0] + bj),
                             (_Float16)(acc0[mt][1] + acc1[mt][1] + bj),
                             (_Float16)(acc0[mt][2] + acc1[mt][2] + bj),
                             (_Float16)(acc0[mt][3] + acc1[mt][3] + bj) };
                ast(xd + ((wave * 1024 + m_l * 64 + mt * 16 + r0) >> 2),
                    __builtin_bit_cast(u64, pk));
            }
            asm volatile("s_waitcnt vmcnt(0)" ::: "memory");
            __syncthreads();
            if (tid == 0)
                __hip_atomic_store(flgp + ((size_t)l * 512 + t) * 32 + wg, 1,
                                   __ATOMIC_RELAXED, __HIP_MEMORY_SCOPE_AGENT);
        }
    }
}

// INP[T,B,H] -> out[B,T,H]
__global__ void transpose_out(const float* __restrict__ inp, float* __restrict__ out) {
#pragma unroll
    for (int i = 0; i < 8; ++i) {
        int f = blockIdx.x * 2048 + i * 256 + threadIdx.x;
        int h4 = f & 127, t = (f >> 7) & 511, b = f >> 16;
        f32x4 v = *(const f32x4*)(inp + ((size_t)t * 64 + b) * 512 + h4 * 4);
        *(f32x4*)(out + ((size_t)b * 512 + t) * 512 + h4 * 4) = v;
    }
}

extern "C" void kernel_launch(void* const* d_in, const int* in_sizes, int n_in,
                              void* d_out, int out_size, void* d_ws, size_t ws_size,
                              hipStream_t stream) {
    const float* x = (const float*)d_in[0];
    const float* W = (const float*)d_in[1];
    const float* U = (const float*)d_in[2];
    const float* b = (const float*)d_in[3];
    float* out = (float*)d_out;
    char* ws = (char*)d_ws;

    constexpr size_t XB_OFF   = 0;                          //  33,554,432
    constexpr size_t INP_OFF  = 33554432;                   //  67,108,864
    constexpr size_t WBF_OFF  = INP_OFF + 67108864;         //   8,388,608
    constexpr size_t UBF_OFF  = WBF_OFF + 8388608;          //   8,388,608
    constexpr size_t FLGH_OFF = UBF_OFF + 8388608;          //     262,656
    constexpr size_t FLGX_OFF = FLGH_OFF + 262656;          //     262,656
    constexpr size_t FLGP_OFF = FLGX_OFF + 262656;          //     262,144
    constexpr size_t HR_OFF   = FLGP_OFF + 262144;          //     524,288
    constexpr size_t XWR_OFF  = HR_OFF + 524288;            //   8,388,608
    constexpr size_t INPB_OFF = XWR_OFF + 8388608;          //   3,145,728
    // total: 130,286,592 bytes (~124.3 MB)

    u64*      XB  = (u64*)(ws + XB_OFF);
    float*    INP = (float*)(ws + INP_OFF);
    u16*      WBF = (u16*)(ws + WBF_OFF);
    u16*      UBF = (u16*)(ws + UBF_OFF);
    int*      flgh = (int*)(ws + FLGH_OFF);
    int*      flgx = (int*)(ws + FLGX_OFF);
    int*      flgp = (int*)(ws + FLGP_OFF);
    u64*      hring = (u64*)(ws + HR_OFF);
    u64*      XWR  = (u64*)(ws + XWR_OFF);
    u64*      INPB = (u64*)(ws + INPB_OFF);

    constexpr int FUSED_LDS = 73728;        // 64K stage (z overlay) + 8K xw
    static int attr_done = 0;
    if (!attr_done) {
        (void)hipFuncSetAttribute((const void*)fused,
                                  hipFuncAttributeMaxDynamicSharedMemorySize, FUSED_LDS);
        attr_done = 1;
    }

    init_flags<<<(196864 + 255) / 256, 256, 0, stream>>>(flgh);
    convert_x<<<2048, 256, 0, stream>>>(x, XB);
    convert_wu<<<dim3(64, 16, 8), 256, 0, stream>>>(W, U, WBF, UBF);
    fused<<<256, 256, FUSED_LDS, stream>>>(XB, WBF, UBF, b, INP, flgh, flgx, flgp,
                                           hring, XWR, INPB, out + 16777216);
    transpose_out<<<2048, 256, 0, stream>>>(INP, out);
}

// Round 5
// 2962.705 us; speedup vs baseline: 5.2172x; 1.3052x over previous
//
#include <hip/hip_runtime.h>
#include <stddef.h>

// LSTM encoder: B=64, T=512, H=512, L=4.
// R10 = R9 with the suspected occupancy deadlock fixed: LDS cut 128KB->64KB
// (2 WGs/CU co-residency restored; R9's 128KB forced exactly-1-WG/CU with
// zero slack on a 256-WG spin-synced launch -> hang). The 64KB stage buffer
// is DELETED via MFMA operand swap: weights = A-operand (LDS, 64KB), the
// activations = B-operand loaded per-lane DIRECTLY from the producer-block
// global rings (2 u64 agent loads per kf). Transposed C/D => thread owns
// (1 batch x 4 consecutive units) => single-u64 ring publishes.
// Kept from R9: spread flags (1 per 128B line), producer-contiguous rings
// [wg][b][16u], in-register gates, decoupled projection (128 rec + 128 proj
// WGs), identical flag DAG (deadlock-free, all cycles net-negative in t):
//   flgh[l][t] -> {flgh[l][t-1], flgp[l][t], flgp[l+1][t-18]}
//   flgp[l][t] -> {flgp[l][t-1], flgx[l-1][t+1], flgh[l][t-8]}
//   flgx[l][t] -> {flgh[l][t], flgp[l+1][t-17]}
// Workspace (~147.5 MB):
//   XB    bf16 [T][32][64][16]      32 MB   x, wg-block layout
//   INP   fp32 [T,B,H]              64 MB   out_0..out_3 in place
//   WBF   bf16 [L][4H][H] (B^T)      8 MB
//   UBF   bf16 [L][4H][H] (B^T)      8 MB
//   FLGH  int  [L][513][32]x32     8.4 MB   recurrence step done (spread)
//   FLGX  int  [L][513][32]x32     8.4 MB   out_l[t-1] published (spread)
//   FLGP  int  [L][512][32]x32     8.4 MB   XW slice ready (spread)
//   HRING bf16 [2][L][32][64][16]  512 KB   h double-ring, wg blocks
//   XWR   fp16 [L][8][32][1024]      8 MB   XW ring, thread-identity
//   INPB  bf16 [3][16][32][64][16]   3 MB   out_l ring, wg blocks

typedef float          f32x4 __attribute__((ext_vector_type(4)));
typedef short          s16x8 __attribute__((ext_vector_type(8)));
typedef unsigned short u16;
typedef u16            u16x4 __attribute__((ext_vector_type(4)));
typedef _Float16       f16x4 __attribute__((ext_vector_type(4)));
typedef unsigned long long u64;
typedef u64            u64x2 __attribute__((ext_vector_type(2)));

__device__ __forceinline__ u16 f2bf(float f) {
    unsigned int u = __builtin_bit_cast(unsigned int, f);
    u += 0x7FFFu + ((u >> 16) & 1u);   // round-to-nearest-even
    return (u16)(u >> 16);
}
__device__ __forceinline__ float sig(float x) { return 1.f / (1.f + __expf(-x)); }
__device__ __forceinline__ float th(float x)  { return 2.f / (1.f + __expf(-2.f * x)) - 1.f; }
__device__ __forceinline__ u64 pk2(float a, float b) {
    return (u64)__builtin_bit_cast(unsigned, a) | ((u64)__builtin_bit_cast(unsigned, b) << 32);
}
__device__ __forceinline__ float lo32(u64 v) { return __builtin_bit_cast(float, (unsigned)v); }
__device__ __forceinline__ float hi32(u64 v) { return __builtin_bit_cast(float, (unsigned)(v >> 32)); }
__device__ __forceinline__ u64 ald(const u64* p) {
    return __hip_atomic_load(p, __ATOMIC_RELAXED, __HIP_MEMORY_SCOPE_AGENT);
}
__device__ __forceinline__ void ast(u64* p, u64 v) {
    __hip_atomic_store(p, v, __ATOMIC_RELAXED, __HIP_MEMORY_SCOPE_AGENT);
}

// all-lane flag poll: lanes with active==false auto-pass
__device__ __forceinline__ void pollflags(const int* p, bool active) {
    while (1) {
        int v = 1;
        if (active) v = __hip_atomic_load(p, __ATOMIC_RELAXED, __HIP_MEMORY_SCOPE_AGENT);
        if (__ballot(v != 0) == ~0ull) break;
    }
}

#define NFLG 6299648   // total ints across flgh+flgx+flgp (contiguous)
__global__ void init_flags(int* __restrict__ flg) {
    int i = blockIdx.x * 256 + threadIdx.x;
    if (i < NFLG) flg[i] = 0;
}

// x[B,T,H] fp32 -> XB[t][wg][b][16u] bf16 (u64 = 4 packed bf16)
__global__ void convert_x(const float* __restrict__ x, u64* __restrict__ XB) {
#pragma unroll
    for (int i = 0; i < 8; ++i) {
        int f = blockIdx.x * 2048 + i * 256 + threadIdx.x;   // u64-quad index
        int h4 = f & 127, b = (f >> 7) & 63, t = f >> 13;
        int wg = h4 >> 2, q = h4 & 3;
        f32x4 v = *(const f32x4*)(x + ((size_t)b * 512 + t) * 512 + h4 * 4);
        u16x4 o = { f2bf(v[0]), f2bf(v[1]), f2bf(v[2]), f2bf(v[3]) };
        XB[(size_t)t * 8192 + wg * 256 + b * 4 + q] = __builtin_bit_cast(u64, o);
    }
}

// W/U [l][k][n] fp32 -> [l][n][k] bf16 (transposed via LDS tile)
__global__ void convert_wu(const float* __restrict__ W, const float* __restrict__ U,
                           u16* __restrict__ WBF, u16* __restrict__ UBF) {
    __shared__ float tl[32][33];
    const int l = blockIdx.z & 3, which = blockIdx.z >> 2;
    const float* src = (which ? U : W) + (size_t)l * 512 * 2048;
    u16* dst = (which ? UBF : WBF) + (size_t)l * 2048 * 512;
    const int n0 = blockIdx.x * 32, k0 = blockIdx.y * 32;
    const int tid = threadIdx.x;
    const int r = tid >> 3, c4 = (tid & 7) * 4;
    f32x4 v = *(const f32x4*)(src + (size_t)(k0 + r) * 2048 + n0 + c4);
    tl[r][c4 + 0] = v[0]; tl[r][c4 + 1] = v[1]; tl[r][c4 + 2] = v[2]; tl[r][c4 + 3] = v[3];
    __syncthreads();
    u16x4 o = { f2bf(tl[c4 + 0][r]), f2bf(tl[c4 + 1][r]), f2bf(tl[c4 + 2][r]), f2bf(tl[c4 + 3][r]) };
    *(u16x4*)(dst + (size_t)(n0 + r) * 512 + k0 + c4) = o;
}

// Fused persistent kernel: 128 recurrence WGs + 128 projection WGs.
__global__ __launch_bounds__(256, 1) void fused(const u64* __restrict__ XB,
                                                const u16* __restrict__ WBF,
                                                const u16* __restrict__ UBF,
                                                const float* __restrict__ bias,
                                                float* __restrict__ INP,
                                                int* __restrict__ flgh,
                                                int* __restrict__ flgx,
                                                int* __restrict__ flgp,
                                                u64* __restrict__ hring,
                                                u64* __restrict__ XWR,
                                                u64* __restrict__ INPB,
                                                float* __restrict__ states) {
    extern __shared__ char lds[];
    char* wlds = lds;    // 64KB: [64 rows = g*16+u'][1024B = 512 k], XOR-swizzled

    const int tid = threadIdx.x, lane = tid & 63, wave = tid >> 6;
    const int m_l = lane & 15, q16 = lane >> 4;
    const int swz = (m_l & 7) << 4;
    const int qh = q16 >> 1, ql = (q16 & 1) << 1;
    const bool rec = blockIdx.x < 128;
    const int l  = rec ? (blockIdx.x & 3) : ((blockIdx.x - 128) & 3);
    const int wg = rec ? (blockIdx.x >> 2) : ((blockIdx.x - 128) >> 2);
    const int brow = wave * 16 + m_l;    // batch row this thread owns
    const int u0 = wg * 16 + q16 * 4;    // first of 4 consecutive units owned

    // weight tile -> LDS: row g*16+u' holds B^T row (g*512 + wg*16 + u'), swizzled
    {
        const u16* wsrc = (rec ? UBF : WBF) + (size_t)l * 1048576;
#pragma unroll
        for (int i = 0; i < 16; ++i) {
            int idx = tid + i * 256;
            int row = idx >> 6, seg = idx & 63;
            int g = row >> 4, up = row & 15;
            s16x8 v = *(const s16x8*)(wsrc + ((size_t)(g * 512 + wg * 16 + up)) * 512 + seg * 8);
            *(s16x8*)(wlds + row * 1024 + ((seg * 16) ^ ((row & 7) << 4))) = v;
        }
    }
    __syncthreads();

    if (rec) {
        // ===================== recurrence role =====================
        u64 xr[4];
        pollflags(flgp + (((size_t)(l * 512 + 0) * 32 + wg) << 5), true);
        {
            const u64* p = XWR + ((size_t)(l * 8 + 0) * 32 + wg) * 1024 + tid * 4;
#pragma unroll
            for (int k = 0; k < 4; ++k) xr[k] = ald(p + k);
        }
        float cr[4] = {0.f, 0.f, 0.f, 0.f};
        float hprev[4] = {0.f, 0.f, 0.f, 0.f};

        for (int t = 0; t <= 512; ++t) {
            // residual loads issued early (certified transitively by flgp[l][t]
            // polled at end of iteration t-1: flgp[l][t] => flgx[l-1][t+1])
            u64 rrv0 = 0, rrv1 = 0;
            u64* ip = (u64*)INP + (size_t)(t > 0 ? t - 1 : 0) * 16384 +
                      (size_t)brow * 256 + (u0 >> 1);
            if (t > 0 && l > 0) { rrv0 = ald(ip); rrv1 = ald(ip + 1); }

            // critical poll: all 32 WGs of this layer finished step t-1
            if (t > 0) pollflags(flgh + (((size_t)(l * 513 + t - 1) * 32 + (lane & 31)) << 5), lane < 32);

            f32x4 acc[4] = {};
            if (t > 0 && t < 512) {
                const u64* hs = hring + (((size_t)((t - 1) & 1) * 4 + l) << 13);
                u64 hlo[16], hhi[16];
#pragma unroll
                for (int kf = 0; kf < 16; ++kf) {
                    const u64* fp = hs + ((kf * 2 + qh) << 8) + brow * 4 + ql;
                    hlo[kf] = ald(fp); hhi[kf] = ald(fp + 1);
                }
#pragma unroll
                for (int kf = 0; kf < 16; ++kf) {
                    u64x2 hv = { hlo[kf], hhi[kf] };
                    s16x8 hf = __builtin_bit_cast(s16x8, hv);
                    const int col = (kf * 64 + q16 * 16) ^ swz;
#pragma unroll
                    for (int g = 0; g < 4; ++g) {
                        s16x8 wf = *(const s16x8*)(wlds + (g * 16 + m_l) * 1024 + col);
                        acc[g] = __builtin_amdgcn_mfma_f32_16x16x32_bf16(wf, hf, acc[g], 0, 0, 0);
                    }
                }
            }

            float hn[4] = {0.f, 0.f, 0.f, 0.f};
            if (t < 512) {
                // gates fully in-register: acc[g][r] = z[g][unit u0+r][batch brow]
#pragma unroll
                for (int r = 0; r < 4; ++r) {
                    f16x4 xw = __builtin_bit_cast(f16x4, xr[r]);
                    float zi = acc[0][r] + (float)xw[0];
                    float zf = acc[1][r] + (float)xw[1];
                    float zg = acc[2][r] + (float)xw[2];
                    float zo = acc[3][r] + (float)xw[3];
                    float cc = sig(zf) * cr[r] + sig(zi) * th(zg);
                    cr[r] = cc;
                    hn[r] = sig(zo) * th(cc);
                }
                // publish h: ONE u64 (4 consecutive units of batch brow)
                u16x4 hb = { f2bf(hn[0]), f2bf(hn[1]), f2bf(hn[2]), f2bf(hn[3]) };
                ast(hring + (((size_t)(t & 1) * 4 + l) << 13) + wg * 256 + brow * 4 + q16,
                    __builtin_bit_cast(u64, hb));
                asm volatile("s_waitcnt vmcnt(0)" ::: "memory");
                __syncthreads();
                if (tid == 0)
                    __hip_atomic_store(flgh + (((size_t)(l * 513 + t) * 32 + wg) << 5), 1,
                                       __ATOMIC_RELAXED, __HIP_MEMORY_SCOPE_AGENT);
            }

            // off-critical: publish out_l[t-1] = hprev (+ residual)
            if (t > 0) {
                if (l < 3 && t >= 17)   // INPB ring backpressure (16-deep)
                    pollflags(flgp + (((size_t)((l + 1) * 512 + t - 17) * 32 + (lane & 31)) << 5), lane < 32);
                float o[4];
#pragma unroll
                for (int r = 0; r < 4; ++r) o[r] = hprev[r];
                if (l > 0) {
                    o[0] += lo32(rrv0); o[1] += hi32(rrv0);
                    o[2] += lo32(rrv1); o[3] += hi32(rrv1);
                }
                ast(ip,     pk2(o[0], o[1]));
                ast(ip + 1, pk2(o[2], o[3]));
                if (l < 3) {
                    u16x4 ob = { f2bf(o[0]), f2bf(o[1]), f2bf(o[2]), f2bf(o[3]) };
                    ast(INPB + (((size_t)l * 16 + ((t - 1) & 15)) << 13) + wg * 256 + brow * 4 + q16,
                        __builtin_bit_cast(u64, ob));
                }
                if (l == 0 && t == 512) {
                    f32x4 sv = { o[0], o[1], o[2], o[3] };
#pragma unroll
                    for (int rep = 0; rep < 4; ++rep)
                        *(f32x4*)&states[(size_t)rep * 32768 + (size_t)brow * 512 + u0] = sv;
                }
                asm volatile("s_waitcnt vmcnt(0)" ::: "memory");
                __syncthreads();
                if (tid == 0 && l < 3)
                    __hip_atomic_store(flgx + (((size_t)(l * 513 + t) * 32 + wg) << 5), 1,
                                       __ATOMIC_RELAXED, __HIP_MEMORY_SCOPE_AGENT);
            }

            // off-critical: XW prefetch for step t+1 (8-deep ring)
            if (t < 511) {
                pollflags(flgp + (((size_t)(l * 512 + t + 1) * 32 + wg) << 5), true);
                const u64* p = XWR + ((size_t)(l * 8 + ((t + 1) & 7)) * 32 + wg) * 1024 + tid * 4;
#pragma unroll
                for (int k = 0; k < 4; ++k) xr[k] = ald(p + k);
            }
#pragma unroll
            for (int r = 0; r < 4; ++r) if (t < 512) hprev[r] = hn[r];
        }
    } else {
        // ===================== projection role =====================
        float bj[4][4];
#pragma unroll
        for (int g = 0; g < 4; ++g)
#pragma unroll
            for (int r = 0; r < 4; ++r)
                bj[g][r] = bias[(size_t)l * 2048 + g * 512 + u0 + r];

        for (int t = 0; t < 512; ++t) {
            // input availability (layer 0's XB ready at launch)
            if (l > 0) pollflags(flgx + (((size_t)((l - 1) * 513 + t + 1) * 32 + (lane & 31)) << 5), lane < 32);
            // issue x loads; backpressure poll overlaps their latency
            u64 xlo[16], xhi[16];
            if (l == 0) {
                const u64* xs = XB + (size_t)t * 8192;
#pragma unroll
                for (int kf = 0; kf < 16; ++kf) {
                    const u64* fp = xs + ((kf * 2 + qh) << 8) + brow * 4 + ql;
                    xlo[kf] = fp[0]; xhi[kf] = fp[1];
                }
            } else {
                const u64* xs = INPB + (((size_t)(l - 1) * 16 + (t & 15)) << 13);
#pragma unroll
                for (int kf = 0; kf < 16; ++kf) {
                    const u64* fp = xs + ((kf * 2 + qh) << 8) + brow * 4 + ql;
                    xlo[kf] = ald(fp); xhi[kf] = ald(fp + 1);
                }
            }
            // XWR ring backpressure (8-deep; rec consumed slot by flgh[l][t-8])
            if (t >= 8) pollflags(flgh + (((size_t)(l * 513 + t - 8) * 32 + wg) << 5), true);

            f32x4 acc[4] = {};
#pragma unroll
            for (int kf = 0; kf < 16; ++kf) {
                u64x2 xv = { xlo[kf], xhi[kf] };
                s16x8 xf = __builtin_bit_cast(s16x8, xv);
                const int col = (kf * 64 + q16 * 16) ^ swz;
#pragma unroll
                for (int g = 0; g < 4; ++g) {
                    s16x8 wf = *(const s16x8*)(wlds + (g * 16 + m_l) * 1024 + col);
                    acc[g] = __builtin_amdgcn_mfma_f32_16x16x32_bf16(wf, xf, acc[g], 0, 0, 0);
                }
            }

            // epilogue: {i,f,g,o} fp16 packed per u64, thread-identity layout
            u64* xd = XWR + ((size_t)(l * 8 + (t & 7)) * 32 + wg) * 1024 + tid * 4;
#pragma unroll
            for (int r = 0; r < 4; ++r) {
                f16x4 pk = { (_Float16)(acc[0][r] + bj[0][r]), (_Float16)(acc[1][r] + bj[1][r]),
                             (_Float16)(acc[2][r] + bj[2][r]), (_Float16)(acc[3][r] + bj[3][r]) };
                ast(xd + r, __builtin_bit_cast(u64, pk));
            }
            asm volatile("s_waitcnt vmcnt(0)" ::: "memory");
            __syncthreads();
            if (tid == 0)
                __hip_atomic_store(flgp + (((size_t)(l * 512 + t) * 32 + wg) << 5), 1,
                                   __ATOMIC_RELAXED, __HIP_MEMORY_SCOPE_AGENT);
        }
    }
}

// INP[T,B,H] -> out[B,T,H]
__global__ void transpose_out(const float* __restrict__ inp, float* __restrict__ out) {
#pragma unroll
    for (int i = 0; i < 8; ++i) {
        int f = blockIdx.x * 2048 + i * 256 + threadIdx.x;
        int h4 = f & 127, t = (f >> 7) & 511, b = f >> 16;
        f32x4 v = *(const f32x4*)(inp + ((size_t)t * 64 + b) * 512 + h4 * 4);
        *(f32x4*)(out + ((size_t)b * 512 + t) * 512 + h4 * 4) = v;
    }
}

extern "C" void kernel_launch(void* const* d_in, const int* in_sizes, int n_in,
                              void* d_out, int out_size, void* d_ws, size_t ws_size,
                              hipStream_t stream) {
    const float* x = (const float*)d_in[0];
    const float* W = (const float*)d_in[1];
    const float* U = (const float*)d_in[2];
    const float* b = (const float*)d_in[3];
    float* out = (float*)d_out;
    char* ws = (char*)d_ws;

    constexpr size_t XB_OFF   = 0;                          //  33,554,432
    constexpr size_t INP_OFF  = 33554432;                   //  67,108,864
    constexpr size_t WBF_OFF  = INP_OFF + 67108864;         //   8,388,608
    constexpr size_t UBF_OFF  = WBF_OFF + 8388608;          //   8,388,608
    constexpr size_t FLGH_OFF = UBF_OFF + 8388608;          //   8,404,992
    constexpr size_t FLGX_OFF = FLGH_OFF + 8404992;         //   8,404,992
    constexpr size_t FLGP_OFF = FLGX_OFF + 8404992;         //   8,388,608
    constexpr size_t HR_OFF   = FLGP_OFF + 8388608;         //     524,288
    constexpr size_t XWR_OFF  = HR_OFF + 524288;            //   8,388,608
    constexpr size_t INPB_OFF = XWR_OFF + 8388608;          //   3,145,728
    // total: 154,697,728 bytes (~147.5 MB)

    u64*      XB  = (u64*)(ws + XB_OFF);
    float*    INP = (float*)(ws + INP_OFF);
    u16*      WBF = (u16*)(ws + WBF_OFF);
    u16*      UBF = (u16*)(ws + UBF_OFF);
    int*      flgh = (int*)(ws + FLGH_OFF);
    int*      flgx = (int*)(ws + FLGX_OFF);
    int*      flgp = (int*)(ws + FLGP_OFF);
    u64*      hring = (u64*)(ws + HR_OFF);
    u64*      XWR  = (u64*)(ws + XWR_OFF);
    u64*      INPB = (u64*)(ws + INPB_OFF);

    constexpr int FUSED_LDS = 65536;        // weights only -> 2 WGs/CU
    static int attr_done = 0;
    if (!attr_done) {
        (void)hipFuncSetAttribute((const void*)fused,
                                  hipFuncAttributeMaxDynamicSharedMemorySize, FUSED_LDS);
        attr_done = 1;
    }

    init_flags<<<(NFLG + 255) / 256, 256, 0, stream>>>(flgh);
    convert_x<<<2048, 256, 0, stream>>>(x, XB);
    convert_wu<<<dim3(64, 16, 8), 256, 0, stream>>>(W, U, WBF, UBF);
    fused<<<256, 256, FUSED_LDS, stream>>>(XB, WBF, UBF, b, INP, flgh, flgx, flgp,
                                           hring, XWR, INPB, out + 16777216);
    transpose_out<<<2048, 256, 0, stream>>>(INP, out);
}

// Round 6
// 2736.272 us; speedup vs baseline: 5.6490x; 1.0828x over previous
//
#include <hip/hip_runtime.h>
#include <stddef.h>

// LSTM encoder: B=64, T=512, H=512, L=4.
// R11 = R10 with the beat stripped to minimum fabric round-trips:
//  - ONE merged poll per rec iteration (single ballot loop): lanes 0-31
//    flgh[l][t-1], lanes 32-62 INPB backpressure flgp[l+1][t-17][0..30],
//    lane 63 dual-load {flgp[l+1][t-17][31], flgp[l][t+1][wg] xw-ready}.
//  - Delayed flgx raise: INP/INPB publish has NO drain; its stores are
//    certified by the NEXT iteration's critical vmcnt(0), and flgx[l][t-1]
//    is raised together with flgh[l][t]. (t=512 epilogue raises the
//    pending flgx[l][511] and flgx[l][512].)
//  - Proj raises flgp[l][t-1] right after MFMA: in-order vmcnt retirement
//    proves iter-(t-1) XWR stores are complete once iter-t loads are
//    consumed, so the vmcnt(0) there is ~free (no drain in proj beat).
//  - XWR prefetch for t+1 issued immediately after the merged poll (lands
//    under h-load + MFMA).
// Flag DAG (re-audited, all cycles net-negative in t => deadlock-free):
//   rec_l[t]  <- rec_l[t-1], proj_l[t+2] (flgp[l][t+1]), proj_{l+1}[t-16]
//   proj_l[t] <- proj_l[t-1], rec_{l-1}[t+2] (flgx[l-1][t+1]), rec_l[t-8]
//   upward chain terminates at proj_0 (reads XB, no flgx dep).
// Everything else = R10: 128 rec + 128 proj WGs, weights-in-LDS (64KB,
// 2 WGs/CU), activations as per-lane B-frag ring loads, spread flags,
// producer-contiguous rings, in-register gates, single-u64 publishes.
// Workspace (~147.5 MB): XB 32MB | INP 64MB | WBF/UBF 8+8MB |
//   FLGH/FLGX/FLGP 8.4MB ea (spread) | HRING 512KB | XWR 8MB | INPB 3MB

typedef float          f32x4 __attribute__((ext_vector_type(4)));
typedef short          s16x8 __attribute__((ext_vector_type(8)));
typedef unsigned short u16;
typedef u16            u16x4 __attribute__((ext_vector_type(4)));
typedef _Float16       f16x4 __attribute__((ext_vector_type(4)));
typedef unsigned long long u64;
typedef u64            u64x2 __attribute__((ext_vector_type(2)));

__device__ __forceinline__ u16 f2bf(float f) {
    unsigned int u = __builtin_bit_cast(unsigned int, f);
    u += 0x7FFFu + ((u >> 16) & 1u);   // round-to-nearest-even
    return (u16)(u >> 16);
}
__device__ __forceinline__ float sig(float x) { return 1.f / (1.f + __expf(-x)); }
__device__ __forceinline__ float th(float x)  { return 2.f / (1.f + __expf(-2.f * x)) - 1.f; }
__device__ __forceinline__ u64 pk2(float a, float b) {
    return (u64)__builtin_bit_cast(unsigned, a) | ((u64)__builtin_bit_cast(unsigned, b) << 32);
}
__device__ __forceinline__ float lo32(u64 v) { return __builtin_bit_cast(float, (unsigned)v); }
__device__ __forceinline__ float hi32(u64 v) { return __builtin_bit_cast(float, (unsigned)(v >> 32)); }
__device__ __forceinline__ u64 ald(const u64* p) {
    return __hip_atomic_load(p, __ATOMIC_RELAXED, __HIP_MEMORY_SCOPE_AGENT);
}
__device__ __forceinline__ void ast(u64* p, u64 v) {
    __hip_atomic_store(p, v, __ATOMIC_RELAXED, __HIP_MEMORY_SCOPE_AGENT);
}
__device__ __forceinline__ void raiseflag(int* p) {
    __hip_atomic_store(p, 1, __ATOMIC_RELAXED, __HIP_MEMORY_SCOPE_AGENT);
}

// all-lane flag poll: lanes with active==false auto-pass
__device__ __forceinline__ void pollflags(const int* p, bool active) {
    while (1) {
        int v = 1;
        if (active) v = __hip_atomic_load(p, __ATOMIC_RELAXED, __HIP_MEMORY_SCOPE_AGENT);
        if (__ballot(v != 0) == ~0ull) break;
    }
}

#define NFLG 6299648   // total ints across flgh+flgx+flgp (contiguous)
__global__ void init_flags(int* __restrict__ flg) {
    int i = blockIdx.x * 256 + threadIdx.x;
    if (i < NFLG) flg[i] = 0;
}

// x[B,T,H] fp32 -> XB[t][wg][b][16u] bf16 (u64 = 4 packed bf16)
__global__ void convert_x(const float* __restrict__ x, u64* __restrict__ XB) {
#pragma unroll
    for (int i = 0; i < 8; ++i) {
        int f = blockIdx.x * 2048 + i * 256 + threadIdx.x;   // u64-quad index
        int h4 = f & 127, b = (f >> 7) & 63, t = f >> 13;
        int wg = h4 >> 2, q = h4 & 3;
        f32x4 v = *(const f32x4*)(x + ((size_t)b * 512 + t) * 512 + h4 * 4);
        u16x4 o = { f2bf(v[0]), f2bf(v[1]), f2bf(v[2]), f2bf(v[3]) };
        XB[(size_t)t * 8192 + wg * 256 + b * 4 + q] = __builtin_bit_cast(u64, o);
    }
}

// W/U [l][k][n] fp32 -> [l][n][k] bf16 (transposed via LDS tile)
__global__ void convert_wu(const float* __restrict__ W, const float* __restrict__ U,
                           u16* __restrict__ WBF, u16* __restrict__ UBF) {
    __shared__ float tl[32][33];
    const int l = blockIdx.z & 3, which = blockIdx.z >> 2;
    const float* src = (which ? U : W) + (size_t)l * 512 * 2048;
    u16* dst = (which ? UBF : WBF) + (size_t)l * 2048 * 512;
    const int n0 = blockIdx.x * 32, k0 = blockIdx.y * 32;
    const int tid = threadIdx.x;
    const int r = tid >> 3, c4 = (tid & 7) * 4;
    f32x4 v = *(const f32x4*)(src + (size_t)(k0 + r) * 2048 + n0 + c4);
    tl[r][c4 + 0] = v[0]; tl[r][c4 + 1] = v[1]; tl[r][c4 + 2] = v[2]; tl[r][c4 + 3] = v[3];
    __syncthreads();
    u16x4 o = { f2bf(tl[c4 + 0][r]), f2bf(tl[c4 + 1][r]), f2bf(tl[c4 + 2][r]), f2bf(tl[c4 + 3][r]) };
    *(u16x4*)(dst + (size_t)(n0 + r) * 512 + k0 + c4) = o;
}

// Fused persistent kernel: 128 recurrence WGs + 128 projection WGs.
__global__ __launch_bounds__(256, 1) void fused(const u64* __restrict__ XB,
                                                const u16* __restrict__ WBF,
                                                const u16* __restrict__ UBF,
                                                const float* __restrict__ bias,
                                                float* __restrict__ INP,
                                                int* __restrict__ flgh,
                                                int* __restrict__ flgx,
                                                int* __restrict__ flgp,
                                                u64* __restrict__ hring,
                                                u64* __restrict__ XWR,
                                                u64* __restrict__ INPB,
                                                float* __restrict__ states) {
    extern __shared__ char lds[];
    char* wlds = lds;    // 64KB: [64 rows = g*16+u'][1024B = 512 k], XOR-swizzled

    const int tid = threadIdx.x, lane = tid & 63, wave = tid >> 6;
    const int m_l = lane & 15, q16 = lane >> 4;
    const int swz = (m_l & 7) << 4;
    const int qh = q16 >> 1, ql = (q16 & 1) << 1;
    const bool rec = blockIdx.x < 128;
    const int l  = rec ? (blockIdx.x & 3) : ((blockIdx.x - 128) & 3);
    const int wg = rec ? (blockIdx.x >> 2) : ((blockIdx.x - 128) >> 2);
    const int brow = wave * 16 + m_l;    // batch row this thread owns
    const int u0 = wg * 16 + q16 * 4;    // first of 4 consecutive units owned

    // weight tile -> LDS: row g*16+u' holds B^T row (g*512 + wg*16 + u'), swizzled
    {
        const u16* wsrc = (rec ? UBF : WBF) + (size_t)l * 1048576;
#pragma unroll
        for (int i = 0; i < 16; ++i) {
            int idx = tid + i * 256;
            int row = idx >> 6, seg = idx & 63;
            int g = row >> 4, up = row & 15;
            s16x8 v = *(const s16x8*)(wsrc + ((size_t)(g * 512 + wg * 16 + up)) * 512 + seg * 8);
            *(s16x8*)(wlds + row * 1024 + ((seg * 16) ^ ((row & 7) << 4))) = v;
        }
    }
    __syncthreads();

    if (rec) {
        // ===================== recurrence role =====================
        u64 xr[4];
        pollflags(flgp + (((size_t)(l * 512 + 0) * 32 + wg) << 5), true);
        {
            const u64* p = XWR + ((size_t)(l * 8 + 0) * 32 + wg) * 1024 + tid * 4;
#pragma unroll
            for (int k = 0; k < 4; ++k) xr[k] = ald(p + k);
        }
        float cr[4] = {0.f, 0.f, 0.f, 0.f};
        float hprev[4] = {0.f, 0.f, 0.f, 0.f};

        for (int t = 0; t <= 512; ++t) {
            // residual loads issued early (certified transitively: flgp[l][t]
            // (polled at iter t-1) => proj_l iter t+1 => flgx[l-1][t+1])
            u64 rrv0 = 0, rrv1 = 0;
            u64* ip = (u64*)INP + (size_t)(t > 0 ? t - 1 : 0) * 16384 +
                      (size_t)brow * 256 + (u0 >> 1);
            if (t > 0 && l > 0) { rrv0 = ald(ip); rrv1 = ald(ip + 1); }

            // ---- merged poll (single ballot loop, one RT) ----
            {
                const int tb = (t >= 17) ? t - 17 : 0;
                const int tc = (t < 511) ? t + 1 : 0;
                const int* pA;
                bool actA;
                if (lane < 32) {
                    pA = flgh + (((size_t)(l * 513 + (t > 0 ? t - 1 : 0)) * 32 + lane) << 5);
                    actA = (t > 0);
                } else {
                    const int lp = (l < 3) ? l + 1 : 3;
                    pA = flgp + (((size_t)(lp * 512 + tb) * 32 + (lane - 32)) << 5);
                    actA = (l < 3) && (t >= 17);
                }
                const int* pB = flgp + (((size_t)(l * 512 + tc) * 32 + wg) << 5);
                const bool actB = (lane == 63) && (t < 511);
                while (1) {
                    int v = 1;
                    if (actA) v = __hip_atomic_load(pA, __ATOMIC_RELAXED, __HIP_MEMORY_SCOPE_AGENT);
                    if (actB) v &= __hip_atomic_load(pB, __ATOMIC_RELAXED, __HIP_MEMORY_SCOPE_AGENT);
                    if (__ballot(v != 0) == ~0ull) break;
                }
            }

            // xw prefetch for t+1 (certified by lane-63 poll; lands under MFMA)
            u64 xrn[4] = {0, 0, 0, 0};
            if (t < 511) {
                const u64* p = XWR + ((size_t)(l * 8 + ((t + 1) & 7)) * 32 + wg) * 1024 + tid * 4;
#pragma unroll
                for (int k = 0; k < 4; ++k) xrn[k] = ald(p + k);
            }

            // ---- critical: h loads + MFMA ----
            f32x4 acc[4] = {};
            if (t > 0 && t < 512) {
                const u64* hs = hring + (((size_t)((t - 1) & 1) * 4 + l) << 13);
                u64 hlo[16], hhi[16];
#pragma unroll
                for (int kf = 0; kf < 16; ++kf) {
                    const u64* fp = hs + ((kf * 2 + qh) << 8) + brow * 4 + ql;
                    hlo[kf] = ald(fp); hhi[kf] = ald(fp + 1);
                }
#pragma unroll
                for (int kf = 0; kf < 16; ++kf) {
                    u64x2 hv = { hlo[kf], hhi[kf] };
                    s16x8 hf = __builtin_bit_cast(s16x8, hv);
                    const int col = (kf * 64 + q16 * 16) ^ swz;
#pragma unroll
                    for (int g = 0; g < 4; ++g) {
                        s16x8 wf = *(const s16x8*)(wlds + (g * 16 + m_l) * 1024 + col);
                        acc[g] = __builtin_amdgcn_mfma_f32_16x16x32_bf16(wf, hf, acc[g], 0, 0, 0);
                    }
                }
            }

            float hn[4] = {0.f, 0.f, 0.f, 0.f};
            if (t < 512) {
                // gates fully in-register: acc[g][r] = z[g][unit u0+r][batch brow]
#pragma unroll
                for (int r = 0; r < 4; ++r) {
                    f16x4 xw = __builtin_bit_cast(f16x4, xr[r]);
                    float zi = acc[0][r] + (float)xw[0];
                    float zf = acc[1][r] + (float)xw[1];
                    float zg = acc[2][r] + (float)xw[2];
                    float zo = acc[3][r] + (float)xw[3];
                    float cc = sig(zf) * cr[r] + sig(zi) * th(zg);
                    cr[r] = cc;
                    hn[r] = sig(zo) * th(cc);
                }
                // publish h: ONE u64 (4 consecutive units of batch brow)
                u16x4 hb = { f2bf(hn[0]), f2bf(hn[1]), f2bf(hn[2]), f2bf(hn[3]) };
                ast(hring + (((size_t)(t & 1) * 4 + l) << 13) + wg * 256 + brow * 4 + q16,
                    __builtin_bit_cast(u64, hb));
                asm volatile("s_waitcnt vmcnt(0)" ::: "memory");   // drains h store
                __syncthreads();                                   // + iter t-1 tail stores
                if (tid == 0) {
                    raiseflag(flgh + (((size_t)(l * 513 + t) * 32 + wg) << 5));
                    if (l < 3 && t >= 2)   // delayed: certifies INP[t-2] (iter t-1 tail)
                        raiseflag(flgx + (((size_t)(l * 513 + t - 1) * 32 + wg) << 5));
                }
            } else {
                asm volatile("s_waitcnt vmcnt(0)" ::: "memory");   // drains iter-511 tail
                __syncthreads();
                if (tid == 0 && l < 3)
                    raiseflag(flgx + (((size_t)(l * 513 + 511) * 32 + wg) << 5));
            }

            // ---- tail: publish out_l[t-1] (NO drain; certified next iter) ----
            if (t > 0) {
                float o[4];
#pragma unroll
                for (int r = 0; r < 4; ++r) o[r] = hprev[r];
                if (l > 0) {
                    o[0] += lo32(rrv0); o[1] += hi32(rrv0);
                    o[2] += lo32(rrv1); o[3] += hi32(rrv1);
                }
                ast(ip,     pk2(o[0], o[1]));
                ast(ip + 1, pk2(o[2], o[3]));
                if (l < 3) {
                    u16x4 ob = { f2bf(o[0]), f2bf(o[1]), f2bf(o[2]), f2bf(o[3]) };
                    ast(INPB + (((size_t)l * 16 + ((t - 1) & 15)) << 13) + wg * 256 + brow * 4 + q16,
                        __builtin_bit_cast(u64, ob));
                }
                if (l == 0 && t == 512) {
                    f32x4 sv = { o[0], o[1], o[2], o[3] };
#pragma unroll
                    for (int rep = 0; rep < 4; ++rep)
                        *(f32x4*)&states[(size_t)rep * 32768 + (size_t)brow * 512 + u0] = sv;
                }
                if (t == 512) {            // final: certify INP[511]
                    asm volatile("s_waitcnt vmcnt(0)" ::: "memory");
                    __syncthreads();
                    if (tid == 0 && l < 3)
                        raiseflag(flgx + (((size_t)(l * 513 + 512) * 32 + wg) << 5));
                }
            }
#pragma unroll
            for (int r = 0; r < 4; ++r) if (t < 512) hprev[r] = hn[r];
            if (t < 511) {
#pragma unroll
                for (int k = 0; k < 4; ++k) xr[k] = xrn[k];
            }
        }
    } else {
        // ===================== projection role =====================
        float bj[4][4];
#pragma unroll
        for (int g = 0; g < 4; ++g)
#pragma unroll
            for (int r = 0; r < 4; ++r)
                bj[g][r] = bias[(size_t)l * 2048 + g * 512 + u0 + r];

        for (int t = 0; t < 512; ++t) {
            // merged poll: lanes 0-31 input availability, lane 32 XWR backpressure
            {
                const int* pA;
                bool actA;
                if (lane < 32) {
                    pA = flgx + (((size_t)((l > 0 ? l - 1 : 0) * 513 + t + 1) * 32 + lane) << 5);
                    actA = (l > 0);
                } else {
                    pA = flgh + (((size_t)(l * 513 + (t >= 8 ? t - 8 : 0)) * 32 + wg) << 5);
                    actA = (lane == 32) && (t >= 8);
                }
                while (1) {
                    int v = 1;
                    if (actA) v = __hip_atomic_load(pA, __ATOMIC_RELAXED, __HIP_MEMORY_SCOPE_AGENT);
                    if (__ballot(v != 0) == ~0ull) break;
                }
            }

            u64 xlo[16], xhi[16];
            if (l == 0) {
                const u64* xs = XB + (size_t)t * 8192;
#pragma unroll
                for (int kf = 0; kf < 16; ++kf) {
                    const u64* fp = xs + ((kf * 2 + qh) << 8) + brow * 4 + ql;
                    xlo[kf] = fp[0]; xhi[kf] = fp[1];
                }
            } else {
                const u64* xs = INPB + (((size_t)(l - 1) * 16 + (t & 15)) << 13);
#pragma unroll
                for (int kf = 0; kf < 16; ++kf) {
                    const u64* fp = xs + ((kf * 2 + qh) << 8) + brow * 4 + ql;
                    xlo[kf] = ald(fp); xhi[kf] = ald(fp + 1);
                }
            }

            f32x4 acc[4] = {};
#pragma unroll
            for (int kf = 0; kf < 16; ++kf) {
                u64x2 xv = { xlo[kf], xhi[kf] };
                s16x8 xf = __builtin_bit_cast(s16x8, xv);
                const int col = (kf * 64 + q16 * 16) ^ swz;
#pragma unroll
                for (int g = 0; g < 4; ++g) {
                    s16x8 wf = *(const s16x8*)(wlds + (g * 16 + m_l) * 1024 + col);
                    acc[g] = __builtin_amdgcn_mfma_f32_16x16x32_bf16(wf, xf, acc[g], 0, 0, 0);
                }
            }

            // delayed flgp raise: iter t-1 XWR stores are provably retired
            // (older than this iter's consumed loads) -> vmcnt(0) ~free here
            asm volatile("s_waitcnt vmcnt(0)" ::: "memory");
            __syncthreads();
            if (tid == 0 && t > 0)
                raiseflag(flgp + (((size_t)(l * 512 + t - 1) * 32 + wg) << 5));

            // epilogue: {i,f,g,o} fp16 packed per u64, thread-identity layout
            u64* xd = XWR + ((size_t)(l * 8 + (t & 7)) * 32 + wg) * 1024 + tid * 4;
#pragma unroll
            for (int r = 0; r < 4; ++r) {
                f16x4 pk = { (_Float16)(acc[0][r] + bj[0][r]), (_Float16)(acc[1][r] + bj[1][r]),
                             (_Float16)(acc[2][r] + bj[2][r]), (_Float16)(acc[3][r] + bj[3][r]) };
                ast(xd + r, __builtin_bit_cast(u64, pk));
            }
        }
        // final slot: drain + raise flgp[l][511]
        asm volatile("s_waitcnt vmcnt(0)" ::: "memory");
        __syncthreads();
        if (tid == 0)
            raiseflag(flgp + (((size_t)(l * 512 + 511) * 32 + wg) << 5));
    }
}

// INP[T,B,H] -> out[B,T,H]
__global__ void transpose_out(const float* __restrict__ inp, float* __restrict__ out) {
#pragma unroll
    for (int i = 0; i < 8; ++i) {
        int f = blockIdx.x * 2048 + i * 256 + threadIdx.x;
        int h4 = f & 127, t = (f >> 7) & 511, b = f >> 16;
        f32x4 v = *(const f32x4*)(inp + ((size_t)t * 64 + b) * 512 + h4 * 4);
        *(f32x4*)(out + ((size_t)b * 512 + t) * 512 + h4 * 4) = v;
    }
}

extern "C" void kernel_launch(void* const* d_in, const int* in_sizes, int n_in,
                              void* d_out, int out_size, void* d_ws, size_t ws_size,
                              hipStream_t stream) {
    const float* x = (const float*)d_in[0];
    const float* W = (const float*)d_in[1];
    const float* U = (const float*)d_in[2];
    const float* b = (const float*)d_in[3];
    float* out = (float*)d_out;
    char* ws = (char*)d_ws;

    constexpr size_t XB_OFF   = 0;                          //  33,554,432
    constexpr size_t INP_OFF  = 33554432;                   //  67,108,864
    constexpr size_t WBF_OFF  = INP_OFF + 67108864;         //   8,388,608
    constexpr size_t UBF_OFF  = WBF_OFF + 8388608;          //   8,388,608
    constexpr size_t FLGH_OFF = UBF_OFF + 8388608;          //   8,404,992
    constexpr size_t FLGX_OFF = FLGH_OFF + 8404992;         //   8,404,992
    constexpr size_t FLGP_OFF = FLGX_OFF + 8404992;         //   8,388,608
    constexpr size_t HR_OFF   = FLGP_OFF + 8388608;         //     524,288
    constexpr size_t XWR_OFF  = HR_OFF + 524288;            //   8,388,608
    constexpr size_t INPB_OFF = XWR_OFF + 8388608;          //   3,145,728
    // total: 154,697,728 bytes (~147.5 MB)

    u64*      XB  = (u64*)(ws + XB_OFF);
    float*    INP = (float*)(ws + INP_OFF);
    u16*      WBF = (u16*)(ws + WBF_OFF);
    u16*      UBF = (u16*)(ws + UBF_OFF);
    int*      flgh = (int*)(ws + FLGH_OFF);
    int*      flgx = (int*)(ws + FLGX_OFF);
    int*      flgp = (int*)(ws + FLGP_OFF);
    u64*      hring = (u64*)(ws + HR_OFF);
    u64*      XWR  = (u64*)(ws + XWR_OFF);
    u64*      INPB = (u64*)(ws + INPB_OFF);

    constexpr int FUSED_LDS = 65536;        // weights only -> 2 WGs/CU
    static int attr_done = 0;
    if (!attr_done) {
        (void)hipFuncSetAttribute((const void*)fused,
                                  hipFuncAttributeMaxDynamicSharedMemorySize, FUSED_LDS);
        attr_done = 1;
    }

    init_flags<<<(NFLG + 255) / 256, 256, 0, stream>>>(flgh);
    convert_x<<<2048, 256, 0, stream>>>(x, XB);
    convert_wu<<<dim3(64, 16, 8), 256, 0, stream>>>(W, U, WBF, UBF);
    fused<<<256, 256, FUSED_LDS, stream>>>(XB, WBF, UBF, b, INP, flgh, flgx, flgp,
                                           hring, XWR, INPB, out + 16777216);
    transpose_out<<<2048, 256, 0, stream>>>(INP, out);
}